// Round 3
// baseline (411.629 us; speedup 1.0000x reference)
//
#include <hip/hip_runtime.h>

// Problem constants: B=2, C=256, planes=64, T=8, D=H=W=16
// spatial per batch S = T*D*H*W = 32768
#define S_TOT 32768

typedef unsigned short ushortT;
typedef __attribute__((ext_vector_type(8))) short short8;
typedef __attribute__((ext_vector_type(4))) float floatx4;

__device__ __forceinline__ ushortT f2bf(float f) {
    unsigned u = __float_as_uint(f);
    u = (u + 0x7fffu + ((u >> 16) & 1u)) >> 16;
    return (ushortT)u;
}
__device__ __forceinline__ float bf2f(ushortT h) {
    return __uint_as_float(((unsigned)h) << 16);
}

// ---------------------------------------------------------------------------
// Prep weights: w1 -> wb1 [cc(8)][q(4)][o(64)][j(8)]  (c = cc*32+q*8+j)
//               w2 -> wb2 [tap(81)][cb(8)][o(64)][j(8)] (c = cb*8+j)
//               w3 -> wb3 [g(8)][o(256)][j(8)]  (g=ks*4+q, c = ks*32+q*8+j)
__global__ __launch_bounds__(256) void k_prep_w(const float* __restrict__ w1,
                                                const float* __restrict__ w2,
                                                const float* __restrict__ w3,
                                                ushortT* __restrict__ wb1,
                                                ushortT* __restrict__ wb2,
                                                ushortT* __restrict__ wb3) {
    int idx = blockIdx.x * 256 + threadIdx.x;
    if (idx < 16384) {
        int e = idx;
        int j = e & 7, o = (e >> 3) & 63, q = (e >> 9) & 3, cc = e >> 11;
        int c = cc * 32 + q * 8 + j;
        wb1[e] = f2bf(w1[o * 256 + c]);
    } else if (idx < 16384 + 331776) {
        int e = idx - 16384;
        int j = e & 7, o = (e >> 3) & 63, cb = (e >> 9) & 7, tap = e >> 12;
        int c = cb * 8 + j;
        wb2[e] = f2bf(w2[((size_t)o * 64 + c) * 81 + tap]);
    } else if (idx < 16384 + 331776 + 16384) {
        int e = idx - 348160;
        int j = e & 7, o = (e >> 3) & 255, g = e >> 11;
        int ks = g >> 2, q = g & 3;
        int c = ks * 32 + q * 8 + j;
        wb3[e] = f2bf(w3[o * 64 + c]);
    }
}

// ---------------------------------------------------------------------------
// K1: conv1x1 256->64 via MFMA. x fp32 converted to bf16 in staging.
// grid 512 = b(2) x nchunk(256 of 128); block 256 = 4 waves; wave wv: o-tile
// wv*16, 8 pos-tiles of 16. Fused bn1 partial stats via atomics.
__global__ __launch_bounds__(256) void k_conv1_mfma(const float* __restrict__ x,
                                                    const ushortT* __restrict__ wb1,
                                                    ushortT* __restrict__ y1bf,
                                                    float* __restrict__ sum1,
                                                    float* __restrict__ sq1) {
    __shared__ __align__(16) ushortT xb[128 * 40];   // [n][c32] stride 40

    int tid = threadIdx.x;
    int blk = blockIdx.x;
    int b  = blk >> 8;
    int n0 = (blk & 255) * 128;

    int lane = tid & 63;
    int wv   = tid >> 6;
    int m    = lane & 15;
    int q    = lane >> 4;

    int c_loc = tid & 31;     // staging channel within chunk
    int ng    = tid >> 5;     // staging n-group (8 groups of 16)

    floatx4 acc[8];
#pragma unroll
    for (int i = 0; i < 8; ++i) acc[i] = (floatx4){0.f, 0.f, 0.f, 0.f};

    for (int cc = 0; cc < 8; ++cc) {
        // A fragment from global (L2-hot): o = wv*16+m, k = q*8+j
        short8 afr = *(const short8*)(wb1 + (((cc * 4 + q) * 64) + wv * 16 + m) * 8);

        __syncthreads();
        // stage B: x[c][n] fp32 -> xb[n][c] bf16
        {
            int c = cc * 32 + c_loc;
            const float* xp = x + ((size_t)(b * 256 + c)) * S_TOT + n0 + ng * 16;
#pragma unroll
            for (int k = 0; k < 4; ++k) {
                float4 v = *(const float4*)(xp + k * 4);
                int nb = ng * 16 + k * 4;
                xb[(nb + 0) * 40 + c_loc] = f2bf(v.x);
                xb[(nb + 1) * 40 + c_loc] = f2bf(v.y);
                xb[(nb + 2) * 40 + c_loc] = f2bf(v.z);
                xb[(nb + 3) * 40 + c_loc] = f2bf(v.w);
            }
        }
        __syncthreads();

#pragma unroll
        for (int pt = 0; pt < 8; ++pt) {
            short8 bfr = *(const short8*)(xb + (pt * 16 + m) * 40 + q * 8);
            acc[pt] = __builtin_amdgcn_mfma_f32_16x16x32_bf16(afr, bfr, acc[pt], 0, 0, 0);
        }
    }

    // store bf16 (unnormalized) + fused bn1 partial stats
#pragma unroll
    for (int pt = 0; pt < 8; ++pt) {
#pragma unroll
        for (int r = 0; r < 4; ++r) {
            int o = wv * 16 + q * 4 + r;
            y1bf[((size_t)(b * 64 + o)) * S_TOT + n0 + pt * 16 + m] = f2bf(acc[pt][r]);
        }
    }
#pragma unroll
    for (int r = 0; r < 4; ++r) {
        float s = 0.f, sq_ = 0.f;
#pragma unroll
        for (int pt = 0; pt < 8; ++pt) {
            float v = acc[pt][r];
            s += v; sq_ += v * v;
        }
#pragma unroll
        for (int mask = 1; mask < 16; mask <<= 1) {
            s   += __shfl_xor(s, mask);
            sq_ += __shfl_xor(sq_, mask);
        }
        if (m == 0) {
            int o = wv * 16 + q * 4 + r;
            atomicAdd(&sum1[o], s);
            atomicAdd(&sq1[o], sq_);
        }
    }
}

// ---------------------------------------------------------------------------
// Prep: yout = bf16(relu(a*yin + b)), a/b computed inline from raw sums (nch=64)
__global__ __launch_bounds__(256) void k_prep(const ushortT* __restrict__ yin,
                                              const float* __restrict__ sum,
                                              const float* __restrict__ sq,
                                              const float* __restrict__ g,
                                              const float* __restrict__ bb,
                                              ushortT* __restrict__ yout) {
    size_t i = ((size_t)blockIdx.x * 256 + threadIdx.x) * 4;
    int c = (int)((i >> 15) & 63);
    const float n = 65536.f;
    float mean = sum[c] / n;
    float var  = sq[c] / n - mean * mean;
    float a  = g[c] * rsqrtf(var + 1e-5f);
    float bs = bb[c] - mean * a;
    ushort4 v = *(const ushort4*)(yin + i);
    ushort4 r;
    r.x = f2bf(fmaxf(a * bf2f(v.x) + bs, 0.f));
    r.y = f2bf(fmaxf(a * bf2f(v.y) + bs, 0.f));
    r.z = f2bf(fmaxf(a * bf2f(v.z) + bs, 0.f));
    r.w = f2bf(fmaxf(a * bf2f(v.w) + bs, 0.f));
    *(ushort4*)(yout + i) = r;
}

// ---------------------------------------------------------------------------
// K3: conv 3x3x3x3, 64->64 as bf16 MFMA implicit GEMM (unchanged core from r2).
// Epilogue now writes bf16 + fused bn2 partial stats.
__global__ __launch_bounds__(256, 2) void k_conv2_mfma(
        const ushortT* __restrict__ y1n,   // [b][c][t][d][h][w] bf16
        const ushortT* __restrict__ wb2,   // [tap][cb][o][j] bf16
        ushortT* __restrict__ y2bf,
        float* __restrict__ sum2,
        float* __restrict__ sq2) {
    __shared__ __align__(16) ushortT xs[180 * 72];

    int tid = threadIdx.x;
    int blk = blockIdx.x;
    int b  = blk >> 8;
    int t  = (blk >> 5) & 7;
    int d  = (blk >> 1) & 15;
    int h0 = (blk & 1) * 8;

    int lane = tid & 63;
    int wv   = tid >> 6;
    int m    = lane & 15;
    int q    = lane >> 4;

    int c2      = tid & 31;
    int prbase  = tid >> 5;

    floatx4 acc[8];
#pragma unroll
    for (int i = 0; i < 8; ++i) acc[i] = (floatx4){0.f, 0.f, 0.f, 0.f};

    const size_t cstride = 32768;
    uint32_t* xsd = (uint32_t*)xs;

    for (int ktd = 0; ktd < 9; ++ktd) {
        int kt = ktd / 3, kd = ktd - kt * 3;
        int tt = t + kt - 1;
        int dd = d + kd - 1;
        bool pv = (tt >= 0 && tt < 8 && dd >= 0 && dd < 16);

        short8 afr[9][2];
#pragma unroll
        for (int khw = 0; khw < 9; ++khw) {
#pragma unroll
            for (int ks = 0; ks < 2; ++ks) {
                int tap = ktd * 9 + khw;
                const ushortT* wp =
                    wb2 + (((size_t)(tap * 8 + ks * 4 + q)) * 64 + wv * 16 + m) * 8;
                afr[khw][ks] = *(const short8*)wp;
            }
        }

        __syncthreads();

        for (int pr = prbase; pr < 10; pr += 8) {
            int hin = h0 + pr - 1;
            uint32_t pack[18];
            if (pv && hin >= 0 && hin < 16) {
                const ushortT* p0 = y1n +
                    (((size_t)(b * 64 + 2 * c2) * 8 + tt) * 16 + dd) * 256 + hin * 16;
                const ushortT* p1 = p0 + cstride;
                uint4 r0 = *(const uint4*)p0;
                uint4 r1 = *(const uint4*)(p0 + 8);
                uint4 s0 = *(const uint4*)p1;
                uint4 s1 = *(const uint4*)(p1 + 8);
                uint32_t ra[8] = {r0.x, r0.y, r0.z, r0.w, r1.x, r1.y, r1.z, r1.w};
                uint32_t sa[8] = {s0.x, s0.y, s0.z, s0.w, s1.x, s1.y, s1.z, s1.w};
                pack[0] = 0; pack[17] = 0;
#pragma unroll
                for (int k = 0; k < 8; ++k) {
                    pack[1 + 2 * k] = (ra[k] & 0xffffu) | (sa[k] << 16);
                    pack[2 + 2 * k] = (ra[k] >> 16) | (sa[k] & 0xffff0000u);
                }
            } else {
#pragma unroll
                for (int k = 0; k < 18; ++k) pack[k] = 0;
            }
            int base = pr * 18 * 36 + c2;
#pragma unroll
            for (int k = 0; k < 18; ++k) xsd[base + k * 36] = pack[k];
        }
        __syncthreads();

#pragma unroll
        for (int khw = 0; khw < 9; ++khw) {
            int kh = khw / 3, kw = khw - kh * 3;
#pragma unroll
            for (int nt = 0; nt < 8; ++nt) {
                int ppos = (nt + kh) * 18 + m + kw;
                const ushortT* bp = xs + ppos * 72 + q * 8;
                short8 b0 = *(const short8*)bp;
                short8 b1 = *(const short8*)(bp + 32);
                acc[nt] = __builtin_amdgcn_mfma_f32_16x16x32_bf16(
                    afr[khw][0], b0, acc[nt], 0, 0, 0);
                acc[nt] = __builtin_amdgcn_mfma_f32_16x16x32_bf16(
                    afr[khw][1], b1, acc[nt], 0, 0, 0);
            }
        }
    }

    // store bf16 + fused bn2 partial stats
#pragma unroll
    for (int nt = 0; nt < 8; ++nt) {
#pragma unroll
        for (int r = 0; r < 4; ++r) {
            int o = wv * 16 + q * 4 + r;
            y2bf[(((size_t)(b * 64 + o) * 8 + t) * 16 + d) * 256 + (h0 + nt) * 16 + m] =
                f2bf(acc[nt][r]);
        }
    }
#pragma unroll
    for (int r = 0; r < 4; ++r) {
        float s = 0.f, sq_ = 0.f;
#pragma unroll
        for (int nt = 0; nt < 8; ++nt) {
            float v = acc[nt][r];
            s += v; sq_ += v * v;
        }
#pragma unroll
        for (int mask = 1; mask < 16; mask <<= 1) {
            s   += __shfl_xor(s, mask);
            sq_ += __shfl_xor(sq_, mask);
        }
        if (m == 0) {
            int o = wv * 16 + q * 4 + r;
            atomicAdd(&sum2[o], s);
            atomicAdd(&sq2[o], sq_);
        }
    }
}

// ---------------------------------------------------------------------------
// K5: conv1x1 64->256 via MFMA; reads normalized bf16 y2n, writes y3 fp32
// (into d_out) + fused bn3 partial stats.
// grid 1024 = b(2) x nchunk(512 of 64); block 256 = 4 waves; wave wv covers
// o in [wv*64, wv*64+64) as 4 tiles, 4 pos-tiles of 16.
__global__ __launch_bounds__(256) void k_conv3_mfma(const ushortT* __restrict__ y2n,
                                                    const ushortT* __restrict__ wb3,
                                                    float* __restrict__ y3,
                                                    float* __restrict__ sum3,
                                                    float* __restrict__ sq3) {
    __shared__ __align__(16) ushortT yb[64 * 72];   // [n][c64] stride 72

    int tid = threadIdx.x;
    int blk = blockIdx.x;
    int b  = blk >> 9;
    int n0 = (blk & 511) * 64;

    int lane = tid & 63;
    int wv   = tid >> 6;
    int m    = lane & 15;
    int q    = lane >> 4;

    // stage y2n: 64 n x 64 c, transposed
    for (int idx = tid; idx < 512; idx += 256) {
        int c = idx >> 3, k = idx & 7;
        uint4 v = *(const uint4*)(y2n + ((size_t)(b * 64 + c)) * S_TOT + n0 + k * 8);
        uint32_t va[4] = {v.x, v.y, v.z, v.w};
#pragma unroll
        for (int p = 0; p < 4; ++p) {
            yb[(k * 8 + 2 * p)     * 72 + c] = (ushortT)(va[p] & 0xffffu);
            yb[(k * 8 + 2 * p + 1) * 72 + c] = (ushortT)(va[p] >> 16);
        }
    }
    __syncthreads();

    floatx4 acc[4][4];
#pragma unroll
    for (int i = 0; i < 4; ++i)
#pragma unroll
        for (int j = 0; j < 4; ++j) acc[i][j] = (floatx4){0.f, 0.f, 0.f, 0.f};

#pragma unroll
    for (int ks = 0; ks < 2; ++ks) {
        short8 afr[4];
#pragma unroll
        for (int ot = 0; ot < 4; ++ot)
            afr[ot] = *(const short8*)(wb3 +
                (((ks * 4 + q) * 256) + wv * 64 + ot * 16 + m) * 8);
#pragma unroll
        for (int pt = 0; pt < 4; ++pt) {
            short8 bfr = *(const short8*)(yb + (pt * 16 + m) * 72 + ks * 32 + q * 8);
#pragma unroll
            for (int ot = 0; ot < 4; ++ot)
                acc[ot][pt] = __builtin_amdgcn_mfma_f32_16x16x32_bf16(
                    afr[ot], bfr, acc[ot][pt], 0, 0, 0);
        }
    }

    // store fp32 + fused bn3 partial stats
#pragma unroll
    for (int ot = 0; ot < 4; ++ot) {
#pragma unroll
        for (int pt = 0; pt < 4; ++pt) {
#pragma unroll
            for (int r = 0; r < 4; ++r) {
                int o = wv * 64 + ot * 16 + q * 4 + r;
                y3[((size_t)(b * 256 + o)) * S_TOT + n0 + pt * 16 + m] = acc[ot][pt][r];
            }
        }
    }
#pragma unroll
    for (int ot = 0; ot < 4; ++ot) {
#pragma unroll
        for (int r = 0; r < 4; ++r) {
            float s = 0.f, sq_ = 0.f;
#pragma unroll
            for (int pt = 0; pt < 4; ++pt) {
                float v = acc[ot][pt][r];
                s += v; sq_ += v * v;
            }
#pragma unroll
            for (int mask = 1; mask < 16; mask <<= 1) {
                s   += __shfl_xor(s, mask);
                sq_ += __shfl_xor(sq_, mask);
            }
            if (m == 0) {
                int o = wv * 64 + ot * 16 + q * 4 + r;
                atomicAdd(&sum3[o], s);
                atomicAdd(&sq3[o], sq_);
            }
        }
    }
}

// ---------------------------------------------------------------------------
// K7: out = relu(bn3(y3) + x), in place on d_out; bn3 scale/shift inline.
__global__ __launch_bounds__(256) void k_final(const float* __restrict__ x,
                                               const float* __restrict__ sum,
                                               const float* __restrict__ sq,
                                               const float* __restrict__ g,
                                               const float* __restrict__ bb,
                                               float* __restrict__ out) {
    size_t i = ((size_t)blockIdx.x * 256 + threadIdx.x) * 4;
    int o = (int)((i >> 15) & 255);
    const float n = 65536.f;
    float mean = sum[o] / n;
    float var  = sq[o] / n - mean * mean;
    float a  = g[o] * rsqrtf(var + 1e-5f);
    float bs = bb[o] - mean * a;
    float4 y  = *(float4*)(out + i);
    float4 xv = *(const float4*)(x + i);
    float4 r;
    r.x = fmaxf(a * y.x + bs + xv.x, 0.f);
    r.y = fmaxf(a * y.y + bs + xv.y, 0.f);
    r.z = fmaxf(a * y.z + bs + xv.z, 0.f);
    r.w = fmaxf(a * y.w + bs + xv.w, 0.f);
    *(float4*)(out + i) = r;
}

// ---------------------------------------------------------------------------
extern "C" void kernel_launch(void* const* d_in, const int* in_sizes, int n_in,
                              void* d_out, int out_size, void* d_ws, size_t ws_size,
                              hipStream_t stream) {
    const float* x  = (const float*)d_in[0];
    const float* w1 = (const float*)d_in[1];
    const float* g1 = (const float*)d_in[2];
    const float* b1 = (const float*)d_in[3];
    const float* w2 = (const float*)d_in[4];
    const float* g2 = (const float*)d_in[5];
    const float* b2 = (const float*)d_in[6];
    const float* w3 = (const float*)d_in[7];
    const float* g3 = (const float*)d_in[8];
    const float* b3 = (const float*)d_in[9];

    char* ws = (char*)d_ws;
    ushortT* y1bf = (ushortT*)(ws);               //  8 MiB
    ushortT* y1n  = (ushortT*)(ws + 8388608);     //  8 MiB
    ushortT* y2bf = (ushortT*)(ws + 16777216);    //  8 MiB
    ushortT* y2n  = (ushortT*)(ws + 25165824);    //  8 MiB
    ushortT* wb1  = (ushortT*)(ws + 33554432);    //  32 KiB
    ushortT* wb2  = (ushortT*)(ws + 33587200);    // 648 KiB
    ushortT* wb3  = (ushortT*)(ws + 34250752);    //  32 KiB
    float*   stats = (float*)(ws + 34283520);     // 768 floats
    float* sum1 = stats;        float* sq1 = stats + 64;
    float* sum2 = stats + 128;  float* sq2 = stats + 192;
    float* sum3 = stats + 256;  float* sq3 = stats + 512;
    float* y3 = (float*)d_out;

    hipMemsetAsync(stats, 0, 768 * sizeof(float), stream);
    k_prep_w    <<<1424,  256, 0, stream>>>(w1, w2, w3, wb1, wb2, wb3);
    k_conv1_mfma<<<512,   256, 0, stream>>>(x, wb1, y1bf, sum1, sq1);
    k_prep      <<<4096,  256, 0, stream>>>(y1bf, sum1, sq1, g1, b1, y1n);
    k_conv2_mfma<<<512,   256, 0, stream>>>(y1n, wb2, y2bf, sum2, sq2);
    k_prep      <<<4096,  256, 0, stream>>>(y2bf, sum2, sq2, g2, b2, y2n);
    k_conv3_mfma<<<1024,  256, 0, stream>>>(y2n, wb3, y3, sum3, sq3);
    k_final     <<<16384, 256, 0, stream>>>(x, sum3, sq3, g3, b3, y3);
}

// Round 4
// 266.950 us; speedup vs baseline: 1.5420x; 1.5420x over previous
//
#include <hip/hip_runtime.h>

// Problem constants: B=2, C=256, planes=64, T=8, D=H=W=16
// spatial per batch S = T*D*H*W = 32768
#define S_TOT 32768

typedef unsigned short ushortT;
typedef __attribute__((ext_vector_type(8))) short short8;
typedef __attribute__((ext_vector_type(4))) float floatx4;

__device__ __forceinline__ ushortT f2bf(float f) {
    unsigned u = __float_as_uint(f);
    u = (u + 0x7fffu + ((u >> 16) & 1u)) >> 16;
    return (ushortT)u;
}
__device__ __forceinline__ float bf2f(ushortT h) {
    return __uint_as_float(((unsigned)h) << 16);
}

// ---------------------------------------------------------------------------
// Prep weights: w1 -> wb1 [cc(8)][q(4)][o(64)][j(8)]  (c = cc*32+q*8+j)
//               w2 -> wb2 [tap(81)][cb(8)][o(64)][j(8)] (c = cb*8+j)
//               w3 -> wb3 [g(8)][o(256)][j(8)]  (g=ks*4+q, c = ks*32+q*8+j)
__global__ __launch_bounds__(256) void k_prep_w(const float* __restrict__ w1,
                                                const float* __restrict__ w2,
                                                const float* __restrict__ w3,
                                                ushortT* __restrict__ wb1,
                                                ushortT* __restrict__ wb2,
                                                ushortT* __restrict__ wb3) {
    int idx = blockIdx.x * 256 + threadIdx.x;
    if (idx < 16384) {
        int e = idx;
        int j = e & 7, o = (e >> 3) & 63, q = (e >> 9) & 3, cc = e >> 11;
        int c = cc * 32 + q * 8 + j;
        wb1[e] = f2bf(w1[o * 256 + c]);
    } else if (idx < 16384 + 331776) {
        int e = idx - 16384;
        int j = e & 7, o = (e >> 3) & 63, cb = (e >> 9) & 7, tap = e >> 12;
        int c = cb * 8 + j;
        wb2[e] = f2bf(w2[((size_t)o * 64 + c) * 81 + tap]);
    } else if (idx < 16384 + 331776 + 16384) {
        int e = idx - 348160;
        int j = e & 7, o = (e >> 3) & 255, g = e >> 11;
        int ks = g >> 2, q = g & 3;
        int c = ks * 32 + q * 8 + j;
        wb3[e] = f2bf(w3[o * 64 + c]);
    }
}

// ---------------------------------------------------------------------------
// Channel stats over bf16 tensor [2][nch][S_TOT]: raw sum and sum-of-squares.
// One block per channel; no atomics.
__global__ __launch_bounds__(256) void k_stats_bf16(const ushortT* __restrict__ y,
                                                    int nch,
                                                    float* __restrict__ sum,
                                                    float* __restrict__ sq) {
    __shared__ float red[8];
    int ch = blockIdx.x, tid = threadIdx.x;
    float s = 0.f, q = 0.f;
    for (int b = 0; b < 2; ++b) {
        const ushortT* p = y + ((size_t)(b * nch + ch)) * S_TOT;
        for (int i = tid * 8; i < S_TOT; i += 256 * 8) {
            uint4 v = *(const uint4*)(p + i);
            uint32_t va[4] = {v.x, v.y, v.z, v.w};
#pragma unroll
            for (int k = 0; k < 4; ++k) {
                float a = bf2f((ushortT)(va[k] & 0xffffu));
                float c = bf2f((ushortT)(va[k] >> 16));
                s += a + c;
                q += a * a + c * c;
            }
        }
    }
#pragma unroll
    for (int off = 32; off; off >>= 1) {
        s += __shfl_down(s, off);
        q += __shfl_down(q, off);
    }
    int wid = tid >> 6;
    if ((tid & 63) == 0) { red[wid] = s; red[4 + wid] = q; }
    __syncthreads();
    if (tid == 0) {
        sum[ch] = red[0] + red[1] + red[2] + red[3];
        sq[ch]  = red[4] + red[5] + red[6] + red[7];
    }
}

// Same for fp32 tensor (y3).
__global__ __launch_bounds__(256) void k_stats_f32(const float* __restrict__ y,
                                                   int nch,
                                                   float* __restrict__ sum,
                                                   float* __restrict__ sq) {
    __shared__ float red[8];
    int ch = blockIdx.x, tid = threadIdx.x;
    float s = 0.f, q = 0.f;
    for (int b = 0; b < 2; ++b) {
        const float* p = y + ((size_t)(b * nch + ch)) * S_TOT;
        for (int i = tid * 4; i < S_TOT; i += 256 * 4) {
            float4 v = *(const float4*)(p + i);
            s += v.x + v.y + v.z + v.w;
            q += v.x * v.x + v.y * v.y + v.z * v.z + v.w * v.w;
        }
    }
#pragma unroll
    for (int off = 32; off; off >>= 1) {
        s += __shfl_down(s, off);
        q += __shfl_down(q, off);
    }
    int wid = tid >> 6;
    if ((tid & 63) == 0) { red[wid] = s; red[4 + wid] = q; }
    __syncthreads();
    if (tid == 0) {
        sum[ch] = red[0] + red[1] + red[2] + red[3];
        sq[ch]  = red[4] + red[5] + red[6] + red[7];
    }
}

// ---------------------------------------------------------------------------
// K1: conv1x1 256->64 via MFMA. x fp32 converted to bf16 in staging.
// grid 512 = b(2) x nchunk(256 of 128); block 256 = 4 waves; wave wv: o-tile
// wv*16, 8 pos-tiles of 16.
__global__ __launch_bounds__(256) void k_conv1_mfma(const float* __restrict__ x,
                                                    const ushortT* __restrict__ wb1,
                                                    ushortT* __restrict__ y1bf) {
    __shared__ __align__(16) ushortT xb[128 * 40];   // [n][c32] stride 40

    int tid = threadIdx.x;
    int blk = blockIdx.x;
    int b  = blk >> 8;
    int n0 = (blk & 255) * 128;

    int lane = tid & 63;
    int wv   = tid >> 6;
    int m    = lane & 15;
    int q    = lane >> 4;

    int c_loc = tid & 31;     // staging channel within chunk
    int ng    = tid >> 5;     // staging n-group (8 groups of 16)

    floatx4 acc[8];
#pragma unroll
    for (int i = 0; i < 8; ++i) acc[i] = (floatx4){0.f, 0.f, 0.f, 0.f};

    for (int cc = 0; cc < 8; ++cc) {
        // A fragment from global (L2-hot): o = wv*16+m, k = q*8+j
        short8 afr = *(const short8*)(wb1 + (((cc * 4 + q) * 64) + wv * 16 + m) * 8);

        __syncthreads();
        // stage B: x[c][n] fp32 -> xb[n][c] bf16
        {
            int c = cc * 32 + c_loc;
            const float* xp = x + ((size_t)(b * 256 + c)) * S_TOT + n0 + ng * 16;
#pragma unroll
            for (int k = 0; k < 4; ++k) {
                float4 v = *(const float4*)(xp + k * 4);
                int nb = ng * 16 + k * 4;
                xb[(nb + 0) * 40 + c_loc] = f2bf(v.x);
                xb[(nb + 1) * 40 + c_loc] = f2bf(v.y);
                xb[(nb + 2) * 40 + c_loc] = f2bf(v.z);
                xb[(nb + 3) * 40 + c_loc] = f2bf(v.w);
            }
        }
        __syncthreads();

#pragma unroll
        for (int pt = 0; pt < 8; ++pt) {
            short8 bfr = *(const short8*)(xb + (pt * 16 + m) * 40 + q * 8);
            acc[pt] = __builtin_amdgcn_mfma_f32_16x16x32_bf16(afr, bfr, acc[pt], 0, 0, 0);
        }
    }

    // store bf16 (unnormalized)
#pragma unroll
    for (int pt = 0; pt < 8; ++pt) {
#pragma unroll
        for (int r = 0; r < 4; ++r) {
            int o = wv * 16 + q * 4 + r;
            y1bf[((size_t)(b * 64 + o)) * S_TOT + n0 + pt * 16 + m] = f2bf(acc[pt][r]);
        }
    }
}

// ---------------------------------------------------------------------------
// Prep: yout = bf16(relu(a*yin + b)), a/b computed inline from raw sums (nch=64)
__global__ __launch_bounds__(256) void k_prep(const ushortT* __restrict__ yin,
                                              const float* __restrict__ sum,
                                              const float* __restrict__ sq,
                                              const float* __restrict__ g,
                                              const float* __restrict__ bb,
                                              ushortT* __restrict__ yout) {
    size_t i = ((size_t)blockIdx.x * 256 + threadIdx.x) * 4;
    int c = (int)((i >> 15) & 63);
    const float n = 65536.f;
    float mean = sum[c] / n;
    float var  = sq[c] / n - mean * mean;
    float a  = g[c] * rsqrtf(var + 1e-5f);
    float bs = bb[c] - mean * a;
    ushort4 v = *(const ushort4*)(yin + i);
    ushort4 r;
    r.x = f2bf(fmaxf(a * bf2f(v.x) + bs, 0.f));
    r.y = f2bf(fmaxf(a * bf2f(v.y) + bs, 0.f));
    r.z = f2bf(fmaxf(a * bf2f(v.z) + bs, 0.f));
    r.w = f2bf(fmaxf(a * bf2f(v.w) + bs, 0.f));
    *(ushort4*)(yout + i) = r;
}

// ---------------------------------------------------------------------------
// K3: conv 3x3x3x3, 64->64 as bf16 MFMA implicit GEMM.
__global__ __launch_bounds__(256, 2) void k_conv2_mfma(
        const ushortT* __restrict__ y1n,   // [b][c][t][d][h][w] bf16
        const ushortT* __restrict__ wb2,   // [tap][cb][o][j] bf16
        ushortT* __restrict__ y2bf) {
    __shared__ __align__(16) ushortT xs[180 * 72];

    int tid = threadIdx.x;
    int blk = blockIdx.x;
    int b  = blk >> 8;
    int t  = (blk >> 5) & 7;
    int d  = (blk >> 1) & 15;
    int h0 = (blk & 1) * 8;

    int lane = tid & 63;
    int wv   = tid >> 6;
    int m    = lane & 15;
    int q    = lane >> 4;

    int c2      = tid & 31;
    int prbase  = tid >> 5;

    floatx4 acc[8];
#pragma unroll
    for (int i = 0; i < 8; ++i) acc[i] = (floatx4){0.f, 0.f, 0.f, 0.f};

    const size_t cstride = 32768;
    uint32_t* xsd = (uint32_t*)xs;

    for (int ktd = 0; ktd < 9; ++ktd) {
        int kt = ktd / 3, kd = ktd - kt * 3;
        int tt = t + kt - 1;
        int dd = d + kd - 1;
        bool pv = (tt >= 0 && tt < 8 && dd >= 0 && dd < 16);

        short8 afr[9][2];
#pragma unroll
        for (int khw = 0; khw < 9; ++khw) {
#pragma unroll
            for (int ks = 0; ks < 2; ++ks) {
                int tap = ktd * 9 + khw;
                const ushortT* wp =
                    wb2 + (((size_t)(tap * 8 + ks * 4 + q)) * 64 + wv * 16 + m) * 8;
                afr[khw][ks] = *(const short8*)wp;
            }
        }

        __syncthreads();

        for (int pr = prbase; pr < 10; pr += 8) {
            int hin = h0 + pr - 1;
            uint32_t pack[18];
            if (pv && hin >= 0 && hin < 16) {
                const ushortT* p0 = y1n +
                    (((size_t)(b * 64 + 2 * c2) * 8 + tt) * 16 + dd) * 256 + hin * 16;
                const ushortT* p1 = p0 + cstride;
                uint4 r0 = *(const uint4*)p0;
                uint4 r1 = *(const uint4*)(p0 + 8);
                uint4 s0 = *(const uint4*)p1;
                uint4 s1 = *(const uint4*)(p1 + 8);
                uint32_t ra[8] = {r0.x, r0.y, r0.z, r0.w, r1.x, r1.y, r1.z, r1.w};
                uint32_t sa[8] = {s0.x, s0.y, s0.z, s0.w, s1.x, s1.y, s1.z, s1.w};
                pack[0] = 0; pack[17] = 0;
#pragma unroll
                for (int k = 0; k < 8; ++k) {
                    pack[1 + 2 * k] = (ra[k] & 0xffffu) | (sa[k] << 16);
                    pack[2 + 2 * k] = (ra[k] >> 16) | (sa[k] & 0xffff0000u);
                }
            } else {
#pragma unroll
                for (int k = 0; k < 18; ++k) pack[k] = 0;
            }
            int base = pr * 18 * 36 + c2;
#pragma unroll
            for (int k = 0; k < 18; ++k) xsd[base + k * 36] = pack[k];
        }
        __syncthreads();

#pragma unroll
        for (int khw = 0; khw < 9; ++khw) {
            int kh = khw / 3, kw = khw - kh * 3;
#pragma unroll
            for (int nt = 0; nt < 8; ++nt) {
                int ppos = (nt + kh) * 18 + m + kw;
                const ushortT* bp = xs + ppos * 72 + q * 8;
                short8 b0 = *(const short8*)bp;
                short8 b1 = *(const short8*)(bp + 32);
                acc[nt] = __builtin_amdgcn_mfma_f32_16x16x32_bf16(
                    afr[khw][0], b0, acc[nt], 0, 0, 0);
                acc[nt] = __builtin_amdgcn_mfma_f32_16x16x32_bf16(
                    afr[khw][1], b1, acc[nt], 0, 0, 0);
            }
        }
    }

    // store bf16
#pragma unroll
    for (int nt = 0; nt < 8; ++nt) {
#pragma unroll
        for (int r = 0; r < 4; ++r) {
            int o = wv * 16 + q * 4 + r;
            y2bf[(((size_t)(b * 64 + o) * 8 + t) * 16 + d) * 256 + (h0 + nt) * 16 + m] =
                f2bf(acc[nt][r]);
        }
    }
}

// ---------------------------------------------------------------------------
// K5: conv1x1 64->256 via MFMA; reads normalized bf16 y2n, writes y3 fp32
// (into d_out).
// grid 1024 = b(2) x nchunk(512 of 64); block 256 = 4 waves; wave wv covers
// o in [wv*64, wv*64+64) as 4 tiles, 4 pos-tiles of 16.
__global__ __launch_bounds__(256) void k_conv3_mfma(const ushortT* __restrict__ y2n,
                                                    const ushortT* __restrict__ wb3,
                                                    float* __restrict__ y3) {
    __shared__ __align__(16) ushortT yb[64 * 72];   // [n][c64] stride 72

    int tid = threadIdx.x;
    int blk = blockIdx.x;
    int b  = blk >> 9;
    int n0 = (blk & 511) * 64;

    int lane = tid & 63;
    int wv   = tid >> 6;
    int m    = lane & 15;
    int q    = lane >> 4;

    // stage y2n: 64 n x 64 c, transposed
    for (int idx = tid; idx < 512; idx += 256) {
        int c = idx >> 3, k = idx & 7;
        uint4 v = *(const uint4*)(y2n + ((size_t)(b * 64 + c)) * S_TOT + n0 + k * 8);
        uint32_t va[4] = {v.x, v.y, v.z, v.w};
#pragma unroll
        for (int p = 0; p < 4; ++p) {
            yb[(k * 8 + 2 * p)     * 72 + c] = (ushortT)(va[p] & 0xffffu);
            yb[(k * 8 + 2 * p + 1) * 72 + c] = (ushortT)(va[p] >> 16);
        }
    }
    __syncthreads();

    floatx4 acc[4][4];
#pragma unroll
    for (int i = 0; i < 4; ++i)
#pragma unroll
        for (int j = 0; j < 4; ++j) acc[i][j] = (floatx4){0.f, 0.f, 0.f, 0.f};

#pragma unroll
    for (int ks = 0; ks < 2; ++ks) {
        short8 afr[4];
#pragma unroll
        for (int ot = 0; ot < 4; ++ot)
            afr[ot] = *(const short8*)(wb3 +
                (((ks * 4 + q) * 256) + wv * 64 + ot * 16 + m) * 8);
#pragma unroll
        for (int pt = 0; pt < 4; ++pt) {
            short8 bfr = *(const short8*)(yb + (pt * 16 + m) * 72 + ks * 32 + q * 8);
#pragma unroll
            for (int ot = 0; ot < 4; ++ot)
                acc[ot][pt] = __builtin_amdgcn_mfma_f32_16x16x32_bf16(
                    afr[ot], bfr, acc[ot][pt], 0, 0, 0);
        }
    }

    // store fp32
#pragma unroll
    for (int ot = 0; ot < 4; ++ot) {
#pragma unroll
        for (int pt = 0; pt < 4; ++pt) {
#pragma unroll
            for (int r = 0; r < 4; ++r) {
                int o = wv * 64 + ot * 16 + q * 4 + r;
                y3[((size_t)(b * 256 + o)) * S_TOT + n0 + pt * 16 + m] = acc[ot][pt][r];
            }
        }
    }
}

// ---------------------------------------------------------------------------
// K7: out = relu(bn3(y3) + x), in place on d_out; bn3 scale/shift inline.
__global__ __launch_bounds__(256) void k_final(const float* __restrict__ x,
                                               const float* __restrict__ sum,
                                               const float* __restrict__ sq,
                                               const float* __restrict__ g,
                                               const float* __restrict__ bb,
                                               float* __restrict__ out) {
    size_t i = ((size_t)blockIdx.x * 256 + threadIdx.x) * 4;
    int o = (int)((i >> 15) & 255);
    const float n = 65536.f;
    float mean = sum[o] / n;
    float var  = sq[o] / n - mean * mean;
    float a  = g[o] * rsqrtf(var + 1e-5f);
    float bs = bb[o] - mean * a;
    float4 y  = *(float4*)(out + i);
    float4 xv = *(const float4*)(x + i);
    float4 r;
    r.x = fmaxf(a * y.x + bs + xv.x, 0.f);
    r.y = fmaxf(a * y.y + bs + xv.y, 0.f);
    r.z = fmaxf(a * y.z + bs + xv.z, 0.f);
    r.w = fmaxf(a * y.w + bs + xv.w, 0.f);
    *(float4*)(out + i) = r;
}

// ---------------------------------------------------------------------------
extern "C" void kernel_launch(void* const* d_in, const int* in_sizes, int n_in,
                              void* d_out, int out_size, void* d_ws, size_t ws_size,
                              hipStream_t stream) {
    const float* x  = (const float*)d_in[0];
    const float* w1 = (const float*)d_in[1];
    const float* g1 = (const float*)d_in[2];
    const float* b1 = (const float*)d_in[3];
    const float* w2 = (const float*)d_in[4];
    const float* g2 = (const float*)d_in[5];
    const float* b2 = (const float*)d_in[6];
    const float* w3 = (const float*)d_in[7];
    const float* g3 = (const float*)d_in[8];
    const float* b3 = (const float*)d_in[9];

    char* ws = (char*)d_ws;
    ushortT* y1bf = (ushortT*)(ws);               //  8 MiB
    ushortT* y1n  = (ushortT*)(ws + 8388608);     //  8 MiB
    ushortT* y2bf = (ushortT*)(ws + 16777216);    //  8 MiB
    ushortT* y2n  = (ushortT*)(ws + 25165824);    //  8 MiB
    ushortT* wb1  = (ushortT*)(ws + 33554432);    //  32 KiB
    ushortT* wb2  = (ushortT*)(ws + 33587200);    // 648 KiB
    ushortT* wb3  = (ushortT*)(ws + 34250752);    //  32 KiB
    float*   stats = (float*)(ws + 34283520);     // 768 floats
    float* sum1 = stats;        float* sq1 = stats + 64;
    float* sum2 = stats + 128;  float* sq2 = stats + 192;
    float* sum3 = stats + 256;  float* sq3 = stats + 512;
    float* y3 = (float*)d_out;

    k_prep_w     <<<1424,  256, 0, stream>>>(w1, w2, w3, wb1, wb2, wb3);
    k_conv1_mfma <<<512,   256, 0, stream>>>(x, wb1, y1bf);
    k_stats_bf16 <<<64,    256, 0, stream>>>(y1bf, 64, sum1, sq1);
    k_prep       <<<4096,  256, 0, stream>>>(y1bf, sum1, sq1, g1, b1, y1n);
    k_conv2_mfma <<<512,   256, 0, stream>>>(y1n, wb2, y2bf);
    k_stats_bf16 <<<64,    256, 0, stream>>>(y2bf, 64, sum2, sq2);
    k_prep       <<<4096,  256, 0, stream>>>(y2bf, sum2, sq2, g2, b2, y2n);
    k_conv3_mfma <<<1024,  256, 0, stream>>>(y2n, wb3, y3);
    k_stats_f32  <<<256,   256, 0, stream>>>(y3, 256, sum3, sq3);
    k_final      <<<16384, 256, 0, stream>>>(x, sum3, sq3, g3, b3, y3);
}